// Round 12
// baseline (363.699 us; speedup 1.0000x reference)
//
#include <hip/hip_runtime.h>
#include <math.h>

#define MID 512
#define KT  16
#define NB  65536
#define G   4096
#define PTS 4128   // 258 blocks * 16 points; table point p holds x = (p-1)/G
#define NBLK 258
#define NKS  32

struct NetP { const float *w1,*b1,*w2,*b2,*w3,*b3; };
struct AllP { NetP n[3]; float* table; };

// ---------------------------------------------------------------------------
// Kernel 0a: transpose W2 (512x512) -> W2T[k][n] per net (slab contiguous).
// ---------------------------------------------------------------------------
__global__ __launch_bounds__(256)
void k_prep(AllP P, float* __restrict__ w2t)
{
    __shared__ float t[32][33];
    const int net = blockIdx.z;
    const float* src = (net == 0) ? P.n[0].w2 : (net == 1) ? P.n[1].w2 : P.n[2].w2;
    float* dst = w2t + (size_t)net * MID * MID;
    const int bx = blockIdx.x * 32, by = blockIdx.y * 32;
    const int tx = threadIdx.x & 31, ty = threadIdx.x >> 5;   // ty 0..7
    #pragma unroll
    for (int j = 0; j < 4; ++j)
        t[ty + 8 * j][tx] = src[(size_t)(by + ty + 8 * j) * MID + bx + tx];
    __syncthreads();
    #pragma unroll
    for (int j = 0; j < 4; ++j)
        dst[(size_t)(bx + ty + 8 * j) * MID + by + tx] = t[tx][ty + 8 * j];
}

// ---------------------------------------------------------------------------
// Kernel 0b: precompute h1 = sin(sin(4*(x*w1+b1))) for every (net, point, k),
// stored in k_siren slab order: h1t[net][blk][ks][kt*16+m]. Removes the
// ~100-cycle dependent sinf chain from k_siren's barrier-bounded stage phase.
// ---------------------------------------------------------------------------
__global__ __launch_bounds__(256)
void k_h1(AllP P, float* __restrict__ h1t)
{
    const int net = blockIdx.y;
    const NetP np = (net == 0) ? P.n[0] : (net == 1) ? P.n[1] : P.n[2];
    const int bid = blockIdx.x;            // 0..8255: blk = bid>>5, ks = bid&31
    const int tid = threadIdx.x;           // kt = tid>>4, m = tid&15
    const int blk = bid >> 5, ks = bid & 31;
    const int kt = tid >> 4,  m  = tid & 15;
    const int k = ks * 16 + kt;
    const float xv = ((float)(blk * 16 + m) - 1.0f) * (1.0f / (float)G);
    const float z = 4.f * fmaf(xv, np.w1[k], np.b1[k]);
    h1t[((size_t)net * (NBLK * NKS) + bid) * 256 + tid] = sinf(sinf(z));
}

// ---------------------------------------------------------------------------
// Kernel 1: fused SIREN — R9 structure verbatim (measured 203us, the best):
// 256 thr, 16 pts/block, 774 blocks, P=4, register prefetch, 2-barrier flow.
// Only change: h1 slab comes prefetched from h1t (1 float/thread) instead of
// being sinf-computed inside the stage phase.
// ---------------------------------------------------------------------------
__global__ __attribute__((amdgpu_waves_per_eu(2, 8))) __launch_bounds__(256)
void k_siren(AllP P, const float* __restrict__ w2t, const float* __restrict__ h1t)
{
    __shared__ float smemA[KT * MID];   // 32 KB: W2T slab [kt][n] / layer3 h2
    __shared__ float hlds[KT * 16];     // 1 KB: h1 slab [kt][m]

    const int tid = threadIdx.x;
    const int net = blockIdx.y;
    const int m0  = blockIdx.x * 16;
    NetP np;
    if (net == 0)      np = P.n[0];
    else if (net == 1) np = P.n[1];
    else               np = P.n[2];
    const float* wslab  = w2t + (size_t)net * MID * MID;
    const float* h1base = h1t + ((size_t)net * (NBLK * NKS) + (size_t)blockIdx.x * NKS) * 256;

    const int c  = tid & 63;
    const int pg = tid >> 6;    // wave id 0..3 -> points pg*4 .. pg*4+3

#define ACC_DECL(i) float4 a##i##lo = make_float4(0.f,0.f,0.f,0.f); \
                    float4 a##i##hi = make_float4(0.f,0.f,0.f,0.f);
    ACC_DECL(0) ACC_DECL(1) ACC_DECL(2) ACC_DECL(3)

#define FMA8(i, hv) \
        a##i##lo.x = fmaf(hv, wa.x, a##i##lo.x); a##i##lo.y = fmaf(hv, wa.y, a##i##lo.y); \
        a##i##lo.z = fmaf(hv, wa.z, a##i##lo.z); a##i##lo.w = fmaf(hv, wa.w, a##i##lo.w); \
        a##i##hi.x = fmaf(hv, wb.x, a##i##hi.x); a##i##hi.y = fmaf(hv, wb.y, a##i##hi.y); \
        a##i##hi.z = fmaf(hv, wb.z, a##i##hi.z); a##i##hi.w = fmaf(hv, wb.w, a##i##hi.w);

    // prefetch registers: W slab float4 #(q*256 + tid), q=0..7, + 1 h float
    float4 r0, r1, r2, r3, r4, r5, r6, r7;
    float  hr;
    {
        const float* s0 = wslab + tid * 4;
        r0 = *reinterpret_cast<const float4*>(s0 + 0 * 1024);
        r1 = *reinterpret_cast<const float4*>(s0 + 1 * 1024);
        r2 = *reinterpret_cast<const float4*>(s0 + 2 * 1024);
        r3 = *reinterpret_cast<const float4*>(s0 + 3 * 1024);
        r4 = *reinterpret_cast<const float4*>(s0 + 4 * 1024);
        r5 = *reinterpret_cast<const float4*>(s0 + 5 * 1024);
        r6 = *reinterpret_cast<const float4*>(s0 + 6 * 1024);
        r7 = *reinterpret_cast<const float4*>(s0 + 7 * 1024);
        hr = h1base[tid];
    }

    for (int ks = 0; ks < MID / KT; ++ks) {
        __syncthreads();   // (A) all waves done READING previous slab
        {   // write slab ks from prefetch regs (16B/lane contiguous, 0-conflict)
            float* d0 = &smemA[tid * 4];
            *reinterpret_cast<float4*>(d0 + 0 * 1024) = r0;
            *reinterpret_cast<float4*>(d0 + 1 * 1024) = r1;
            *reinterpret_cast<float4*>(d0 + 2 * 1024) = r2;
            *reinterpret_cast<float4*>(d0 + 3 * 1024) = r3;
            *reinterpret_cast<float4*>(d0 + 4 * 1024) = r4;
            *reinterpret_cast<float4*>(d0 + 5 * 1024) = r5;
            *reinterpret_cast<float4*>(d0 + 6 * 1024) = r6;
            *reinterpret_cast<float4*>(d0 + 7 * 1024) = r7;
            hlds[tid] = hr;   // slab order [kt*16+m] by construction
        }
        __syncthreads();   // (B) slab ks visible

        if (ks + 1 < MID / KT) {   // issue loads for slab ks+1 (consumed next (A))
            const float* s1 = wslab + (size_t)(ks + 1) * KT * MID + tid * 4;
            r0 = *reinterpret_cast<const float4*>(s1 + 0 * 1024);
            r1 = *reinterpret_cast<const float4*>(s1 + 1 * 1024);
            r2 = *reinterpret_cast<const float4*>(s1 + 2 * 1024);
            r3 = *reinterpret_cast<const float4*>(s1 + 3 * 1024);
            r4 = *reinterpret_cast<const float4*>(s1 + 4 * 1024);
            r5 = *reinterpret_cast<const float4*>(s1 + 5 * 1024);
            r6 = *reinterpret_cast<const float4*>(s1 + 6 * 1024);
            r7 = *reinterpret_cast<const float4*>(s1 + 7 * 1024);
            hr = h1base[(ks + 1) * 256 + tid];
        }

        #pragma unroll
        for (int kt = 0; kt < KT; ++kt) {
            const float4 h  = *reinterpret_cast<const float4*>(&hlds[kt * 16 + pg * 4]);
            const float4 wa = *reinterpret_cast<const float4*>(&smemA[kt * MID + c * 4]);
            const float4 wb = *reinterpret_cast<const float4*>(&smemA[kt * MID + 256 + c * 4]);
            FMA8(0, h.x) FMA8(1, h.y) FMA8(2, h.z) FMA8(3, h.w)
        }
    }
    __syncthreads();

    {   // epilogue: h2 = sin(sin(4*(z + b2)))
        const float4 ba = *reinterpret_cast<const float4*>(np.b2 + c * 4);
        const float4 bb = *reinterpret_cast<const float4*>(np.b2 + 256 + c * 4);
#define SS1(v, b) v = sinf(sinf(4.f * ((v) + (b))));
#define SSROW(i) \
        SS1(a##i##lo.x, ba.x) SS1(a##i##lo.y, ba.y) SS1(a##i##lo.z, ba.z) SS1(a##i##lo.w, ba.w) \
        SS1(a##i##hi.x, bb.x) SS1(a##i##hi.y, bb.y) SS1(a##i##hi.z, bb.z) SS1(a##i##hi.w, bb.w)
        SSROW(0) SSROW(1) SSROW(2) SSROW(3)
    }

    // layer 3: two half-passes (cols 0..255 = lo accs, 256..511 = hi accs)
    float2 acc3 = make_float2(0.f, 0.f);
    const int m  = tid & 15;   // point
    const int jg = tid >> 4;   // 0..15 -> outputs jg*2, jg*2+1
    const float* w3a = np.w3 + (size_t)(jg * 2) * MID;
    const float* w3b = w3a + MID;

#define L3STORE(i, sfx) { const int mr = pg * 4 + i; \
    *reinterpret_cast<float4*>(&smemA[mr * 256 + ((c ^ mr) & 63) * 4]) = a##i##sfx; }

#define L3PASS(p, sfx) { \
    L3STORE(0, sfx) L3STORE(1, sfx) L3STORE(2, sfx) L3STORE(3, sfx) \
    __syncthreads(); \
    _Pragma("unroll 8") \
    for (int qq = 0; qq < 64; ++qq) { \
        const float4 h  = *reinterpret_cast<const float4*>(&smemA[m * 256 + ((qq ^ m) & 63) * 4]); \
        const float4 w0 = *reinterpret_cast<const float4*>(w3a + (p) * 256 + qq * 4); \
        const float4 w1 = *reinterpret_cast<const float4*>(w3b + (p) * 256 + qq * 4); \
        acc3.x = fmaf(h.w,w0.w,fmaf(h.z,w0.z,fmaf(h.y,w0.y,fmaf(h.x,w0.x,acc3.x)))); \
        acc3.y = fmaf(h.w,w1.w,fmaf(h.z,w1.z,fmaf(h.y,w1.y,fmaf(h.x,w1.x,acc3.y)))); \
    } \
    __syncthreads(); }

    L3PASS(0, lo)
    L3PASS(1, hi)

    {   // store point-major: table[net][m0+m][jg*2 .. jg*2+1]
        const float2 b3v = *reinterpret_cast<const float2*>(np.b3 + jg * 2);
        float2 r; r.x = acc3.x + b3v.x; r.y = acc3.y + b3v.y;
        *reinterpret_cast<float2*>(
            P.table + ((size_t)net * PTS + (m0 + m)) * 32 + jg * 2) = r;
    }
}

// ---------------------------------------------------------------------------
// Kernel 2: Catmull-Rom interp + Tucker contraction — SCALAR-PIPE core reads.
// rh made provably wave-uniform via readfirstlane, so every core access is a
// uniform address -> s_load_dwordx4 (scalar cache, SGPR operands feed v_fma
// directly). R6's LDS staging issued 2048 ds_read_b128/wave (~12cyc each on
// the single LDS pipe) = the measured 93us wall; scalar loads free that pipe.
// No cs staging, no barriers in the main loop; core (128KB) is L2-resident.
// ---------------------------------------------------------------------------
#define F4MA(acc, s, rp, k) { const float4 _v = (rp)[k]; \
    acc.x = fmaf((s), _v.x, acc.x); acc.y = fmaf((s), _v.y, acc.y); \
    acc.z = fmaf((s), _v.z, acc.z); acc.w = fmaf((s), _v.w, acc.w); }

#define GROW8(Pfx, w, rp, off) \
    F4MA(Pfx##0,(w),rp,(off)+0) F4MA(Pfx##1,(w),rp,(off)+1) \
    F4MA(Pfx##2,(w),rp,(off)+2) F4MA(Pfx##3,(w),rp,(off)+3) \
    F4MA(Pfx##4,(w),rp,(off)+4) F4MA(Pfx##5,(w),rp,(off)+5) \
    F4MA(Pfx##6,(w),rp,(off)+6) F4MA(Pfx##7,(w),rp,(off)+7)

// Catmull-Rom setup: x*G is EXACT in fp32 (power-of-two scale).
#define CRSETUP(x_, iv, c0, c1, c2, c3) \
    int iv; float c0, c1, c2, c3; { \
        float xx = (x_) * (float)G; \
        int i = (int)xx; i = i < 0 ? 0 : (i > G - 1 ? G - 1 : i); iv = i; \
        float t = xx - (float)i; \
        float t2 = t * t, t3 = t2 * t; \
        c0 = fmaf(-0.5f, t3, t2) - 0.5f * t; \
        c1 = fmaf(1.5f, t3, fmaf(-2.5f, t2, 1.f)); \
        c2 = fmaf(-1.5f, t3, fmaf(2.f, t2, 0.5f * t)); \
        c3 = 0.5f * (t3 - t2); }

__global__ __launch_bounds__(256)
void k_ic(const float* __restrict__ table, const float* __restrict__ core,
          const float* __restrict__ x, float* __restrict__ out)
{
    __shared__ float red[256];

    const int tid = threadIdx.x;
    const int ls  = tid & 63;        // local sample
    // rh is constant within a wave; readfirstlane makes that PROVABLE so the
    // compiler selects s_load (scalar pipe) for all core accesses.
    const int rh  = __builtin_amdgcn_readfirstlane(tid >> 6);   // 0..3
    const int g   = blockIdx.x * 64 + ls;

    const float xu = x[(size_t)g * 3 + 0];
    const float xv = x[(size_t)g * 3 + 1];
    const float xw = x[(size_t)g * 3 + 2];

#define DECLZ(Pn) float4 Pn = make_float4(0.f,0.f,0.f,0.f);
    DECLZ(W0) DECLZ(W1) DECLZ(W2) DECLZ(W3) DECLZ(W4) DECLZ(W5) DECLZ(W6) DECLZ(W7)
    DECLZ(V0) DECLZ(V1) DECLZ(V2) DECLZ(V3) DECLZ(V4) DECLZ(V5) DECLZ(V6) DECLZ(V7)
    float2 U0, U1, U2, U3;

    {   // W net (index 2)
        CRSETUP(xw, iw, c0, c1, c2, c3)
        const float4* rp = reinterpret_cast<const float4*>(
            table + ((size_t)2 * PTS + iw) * 32);
        GROW8(W, c0, rp, 0) GROW8(W, c1, rp, 8) GROW8(W, c2, rp, 16) GROW8(W, c3, rp, 24)
    }
    {   // V net (index 1)
        CRSETUP(xv, iv2, c0, c1, c2, c3)
        const float4* rp = reinterpret_cast<const float4*>(
            table + ((size_t)1 * PTS + iv2) * 32);
        GROW8(V, c0, rp, 0) GROW8(V, c1, rp, 8) GROW8(V, c2, rp, 16) GROW8(V, c3, rp, 24)
    }
    {   // U net (index 0): this thread's 8 r-cols = rb*8 + rh*2 + {0,1}
        CRSETUP(xu, iu, c0, c1, c2, c3)
        const float2* up = reinterpret_cast<const float2*>(table + (size_t)iu * 32);
#define UROW(rbv, dst) { \
        const float2 t0 = up[0 * 16 + (rbv) * 4 + rh]; \
        const float2 t1 = up[1 * 16 + (rbv) * 4 + rh]; \
        const float2 t2 = up[2 * 16 + (rbv) * 4 + rh]; \
        const float2 t3 = up[3 * 16 + (rbv) * 4 + rh]; \
        dst.x = fmaf(c0,t0.x,fmaf(c1,t1.x,fmaf(c2,t2.x,c3*t3.x))); \
        dst.y = fmaf(c0,t0.y,fmaf(c1,t1.y,fmaf(c2,t2.y,c3*t3.y))); }
        UROW(0, U0) UROW(1, U1) UROW(2, U2) UROW(3, U3)
    }

    const float4* core4 = reinterpret_cast<const float4*>(core);

#define TQC(rl, s, tq, Wv) { \
    const float4 c4 = core4[(size_t)(rbase + (rl)) * 256 + (s) * 8 + (tq)]; \
    aa = fmaf(Wv.w, c4.w, fmaf(Wv.z, c4.z, fmaf(Wv.y, c4.y, fmaf(Wv.x, c4.x, aa)))); }

#define SONE(rl, s, vcomp) { float aa = 0.f; \
    TQC(rl, s, 0, W0) TQC(rl, s, 1, W1) TQC(rl, s, 2, W2) TQC(rl, s, 3, W3) \
    TQC(rl, s, 4, W4) TQC(rl, s, 5, W5) TQC(rl, s, 6, W6) TQC(rl, s, 7, W7) \
    tracc = fmaf(vcomp, aa, tracc); }

#define SG(rl, sb, Vv) \
    SONE(rl, 4*(sb)+0, Vv.x) SONE(rl, 4*(sb)+1, Vv.y) \
    SONE(rl, 4*(sb)+2, Vv.z) SONE(rl, 4*(sb)+3, Vv.w)

#define RL1(rl, ucomp) { float tracc = 0.f; \
    SG(rl, 0, V0) SG(rl, 1, V1) SG(rl, 2, V2) SG(rl, 3, V3) \
    SG(rl, 4, V4) SG(rl, 5, V5) SG(rl, 6, V6) SG(rl, 7, V7) \
    o = fmaf(ucomp, tracc, o); }

#define RBLOCK(rb) { \
    const int rbase = (rb) * 8 + rh * 2; \
    RL1(0, U##rb.x) RL1(1, U##rb.y) }

    float o = 0.f;
    RBLOCK(0) RBLOCK(1) RBLOCK(2) RBLOCK(3)

    red[tid] = o;
    __syncthreads();
    if (tid < 64)
        out[blockIdx.x * 64 + tid] =
            red[tid] + red[tid + 64] + red[tid + 128] + red[tid + 192];
}

// ---------------------------------------------------------------------------
extern "C" void kernel_launch(void* const* d_in, const int* in_sizes, int n_in,
                              void* d_out, int out_size, void* d_ws, size_t ws_size,
                              hipStream_t stream)
{
    AllP P;
    for (int net = 0; net < 3; ++net) {
        const int b = 1 + net * 6;
        P.n[net].w1 = (const float*)d_in[b + 0];
        P.n[net].b1 = (const float*)d_in[b + 1];
        P.n[net].w2 = (const float*)d_in[b + 2];
        P.n[net].b2 = (const float*)d_in[b + 3];
        P.n[net].w3 = (const float*)d_in[b + 4];
        P.n[net].b3 = (const float*)d_in[b + 5];
    }
    const float* xin  = (const float*)d_in[0];
    const float* core = (const float*)d_in[19];
    float* wsf   = (float*)d_ws;
    float* table = wsf;                            // 3*4128*32     = 1.58 MB
    float* w2t   = wsf + (size_t)3 * PTS * 32;     // 3*512*512     = 3.00 MB
    float* h1t   = w2t + (size_t)3 * MID * MID;    // 3*8256*256    = 25.4 MB
    P.table = table;

    k_prep <<<dim3(16, 16, 3), 256, 0, stream>>>(P, w2t);
    k_h1   <<<dim3(NBLK * NKS, 3), 256, 0, stream>>>(P, h1t);
    k_siren<<<dim3(NBLK, 3), 256, 0, stream>>>(P, w2t, h1t);
    k_ic   <<<NB / 64, 256, 0, stream>>>(table, core, xin, (float*)d_out);
}

// Round 13
// 340.766 us; speedup vs baseline: 1.0673x; 1.0673x over previous
//
#include <hip/hip_runtime.h>
#include <math.h>

#define MID 512
#define KT  16
#define NB  65536
#define G   4096
#define NBLK 65
#define PTS  4160   // 65 blocks * 64 points; table point p holds x = (p-1)/G
#define NKS  32

struct NetP { const float *w1,*b1,*w2,*b2,*w3,*b3; };
struct AllP { NetP n[3]; float* table; };

// ---------------------------------------------------------------------------
// Kernel 0a: transpose W2 (512x512) -> W2T[k][n] per net (slab contiguous).
// ---------------------------------------------------------------------------
__global__ __launch_bounds__(256)
void k_prep(AllP P, float* __restrict__ w2t)
{
    __shared__ float t[32][33];
    const int net = blockIdx.z;
    const float* src = (net == 0) ? P.n[0].w2 : (net == 1) ? P.n[1].w2 : P.n[2].w2;
    float* dst = w2t + (size_t)net * MID * MID;
    const int bx = blockIdx.x * 32, by = blockIdx.y * 32;
    const int tx = threadIdx.x & 31, ty = threadIdx.x >> 5;   // ty 0..7
    #pragma unroll
    for (int j = 0; j < 4; ++j)
        t[ty + 8 * j][tx] = src[(size_t)(by + ty + 8 * j) * MID + bx + tx];
    __syncthreads();
    #pragma unroll
    for (int j = 0; j < 4; ++j)
        dst[(size_t)(bx + ty + 8 * j) * MID + by + tx] = t[tx][ty + 8 * j];
}

// ---------------------------------------------------------------------------
// Kernel 0b: precompute h1 = sin(sin(4*(x*w1+b1))) in k_siren slab order:
// h1t[net][blk][ks][kt*64+m], 1024 floats per (blk,ks).
// ---------------------------------------------------------------------------
__global__ __launch_bounds__(256)
void k_h1(AllP P, float* __restrict__ h1t)
{
    const int net = blockIdx.y;
    const NetP np = (net == 0) ? P.n[0] : (net == 1) ? P.n[1] : P.n[2];
    const int bid = blockIdx.x;            // 0..NBLK*NKS-1
    const int blk = bid >> 5, ks = bid & 31;
    float* dst = h1t + ((size_t)(net * NBLK + blk) * NKS + ks) * 1024;
    #pragma unroll
    for (int r = 0; r < 4; ++r) {
        const int idx = threadIdx.x + r * 256;   // = kt*64 + m
        const int kt = idx >> 6, m = idx & 63;
        const int k = ks * 16 + kt;
        const float xv = ((float)(blk * 64 + m) - 1.0f) * (1.0f / (float)G);
        const float z = 4.f * fmaf(xv, np.w1[k], np.b1[k]);
        dst[idx] = sinf(sinf(z));
    }
}

// ---------------------------------------------------------------------------
// Kernel 1: fused SIREN, 512 threads (8 waves) x 64 points/block, 195 blocks
// (<=1 block/CU, balanced). Thread (pg=tid>>6, c=tid&63): points pg*8..pg*8+7,
// cols {c*4, 256+c*4}. Per kt: 2 broadcast h-reads + 2 strided W-reads feed
// 64 FMAs -> W-reads/FMA HALVED vs R9 (the LDS pipe was ~1.5x oversubscribed).
// Register prefetch (4 f4 W + 2 h floats) keeps the 2-barrier flow.
// Layer 3: four 16-point passes through smemA, XOR swizzle.
// ---------------------------------------------------------------------------
__global__ __attribute__((amdgpu_waves_per_eu(2, 8))) __launch_bounds__(512)
void k_siren(AllP P, const float* __restrict__ w2t, const float* __restrict__ h1t)
{
    __shared__ float smemA[KT * MID];   // 32 KB: W2T slab [kt][n] / layer3 h2
    __shared__ float hlds[KT * 64];     // 4 KB: h1 slab [kt][m]

    const int tid = threadIdx.x;        // 0..511
    const int net = blockIdx.y;
    const int m0  = blockIdx.x * 64;
    NetP np;
    if (net == 0)      np = P.n[0];
    else if (net == 1) np = P.n[1];
    else               np = P.n[2];
    const float* wslab  = w2t + (size_t)net * MID * MID;
    const float* h1base = h1t + ((size_t)(net * NBLK + blockIdx.x) * NKS) * 1024;

    const int c  = tid & 63;
    const int pg = tid >> 6;    // wave id 0..7 -> points pg*8 .. pg*8+7

#define ACC_DECL(i) float4 a##i##lo = make_float4(0.f,0.f,0.f,0.f); \
                    float4 a##i##hi = make_float4(0.f,0.f,0.f,0.f);
    ACC_DECL(0) ACC_DECL(1) ACC_DECL(2) ACC_DECL(3)
    ACC_DECL(4) ACC_DECL(5) ACC_DECL(6) ACC_DECL(7)

#define FMA8(i, hv) \
        a##i##lo.x = fmaf(hv, wa.x, a##i##lo.x); a##i##lo.y = fmaf(hv, wa.y, a##i##lo.y); \
        a##i##lo.z = fmaf(hv, wa.z, a##i##lo.z); a##i##lo.w = fmaf(hv, wa.w, a##i##lo.w); \
        a##i##hi.x = fmaf(hv, wb.x, a##i##hi.x); a##i##hi.y = fmaf(hv, wb.y, a##i##hi.y); \
        a##i##hi.z = fmaf(hv, wb.z, a##i##hi.z); a##i##hi.w = fmaf(hv, wb.w, a##i##hi.w);

    // prefetch: W slab f4 #(j*512 + tid), j=0..3, + 2 h floats
    float4 r0, r1, r2, r3;
    float  h0, h1;
    {
        const float* s0 = wslab + tid * 4;
        r0 = *reinterpret_cast<const float4*>(s0 + 0 * 2048);
        r1 = *reinterpret_cast<const float4*>(s0 + 1 * 2048);
        r2 = *reinterpret_cast<const float4*>(s0 + 2 * 2048);
        r3 = *reinterpret_cast<const float4*>(s0 + 3 * 2048);
        h0 = h1base[tid];
        h1 = h1base[tid + 512];
    }

    for (int ks = 0; ks < MID / KT; ++ks) {
        __syncthreads();   // (A) all waves done READING previous slab
        {   // write slab ks from prefetch regs (16B/lane contiguous, 0-conflict)
            float* d0 = &smemA[tid * 4];
            *reinterpret_cast<float4*>(d0 + 0 * 2048) = r0;
            *reinterpret_cast<float4*>(d0 + 1 * 2048) = r1;
            *reinterpret_cast<float4*>(d0 + 2 * 2048) = r2;
            *reinterpret_cast<float4*>(d0 + 3 * 2048) = r3;
            hlds[tid]       = h0;   // slab order [kt*64+m] by construction
            hlds[tid + 512] = h1;
        }
        __syncthreads();   // (B) slab ks visible

        if (ks + 1 < MID / KT) {   // issue loads for slab ks+1 (consumed next (A))
            const float* s1 = wslab + (size_t)(ks + 1) * KT * MID + tid * 4;
            r0 = *reinterpret_cast<const float4*>(s1 + 0 * 2048);
            r1 = *reinterpret_cast<const float4*>(s1 + 1 * 2048);
            r2 = *reinterpret_cast<const float4*>(s1 + 2 * 2048);
            r3 = *reinterpret_cast<const float4*>(s1 + 3 * 2048);
            h0 = h1base[(ks + 1) * 1024 + tid];
            h1 = h1base[(ks + 1) * 1024 + tid + 512];
        }

        #pragma unroll
        for (int kt = 0; kt < KT; ++kt) {
            const float4 hA = *reinterpret_cast<const float4*>(&hlds[kt * 64 + pg * 8]);
            const float4 hB = *reinterpret_cast<const float4*>(&hlds[kt * 64 + pg * 8 + 4]);
            const float4 wa = *reinterpret_cast<const float4*>(&smemA[kt * MID + c * 4]);
            const float4 wb = *reinterpret_cast<const float4*>(&smemA[kt * MID + 256 + c * 4]);
            FMA8(0, hA.x) FMA8(1, hA.y) FMA8(2, hA.z) FMA8(3, hA.w)
            FMA8(4, hB.x) FMA8(5, hB.y) FMA8(6, hB.z) FMA8(7, hB.w)
        }
    }
    __syncthreads();

    {   // epilogue: h2 = sin(sin(4*(z + b2)))
        const float4 ba = *reinterpret_cast<const float4*>(np.b2 + c * 4);
        const float4 bb = *reinterpret_cast<const float4*>(np.b2 + 256 + c * 4);
#define SS1(v, b) v = sinf(sinf(4.f * ((v) + (b))));
#define SSROW(i) \
        SS1(a##i##lo.x, ba.x) SS1(a##i##lo.y, ba.y) SS1(a##i##lo.z, ba.z) SS1(a##i##lo.w, ba.w) \
        SS1(a##i##hi.x, bb.x) SS1(a##i##hi.y, bb.y) SS1(a##i##hi.z, bb.z) SS1(a##i##hi.w, bb.w)
        SSROW(0) SSROW(1) SSROW(2) SSROW(3) SSROW(4) SSROW(5) SSROW(6) SSROW(7)
    }

    // layer 3: four 16-point passes. Pass p covers points p*16..p*16+15
    // (owner waves pg = 2p, 2p+1). XOR-swizzled smemA:
    // phys f4 (lr, n4) = lr*128 + ((n4 ^ lr) & 127), lr = local row 0..15.
    const int m  = tid & 15;    // local point
    const int jg = tid >> 4;    // 0..31 -> output col jg
    const float* wr = np.w3 + (size_t)jg * MID;
    const float  b3v = np.b3[jg];

#define L3ST(i) { const int lr = lrb + (i); \
    *reinterpret_cast<float4*>(&smemA[lr * 512 + (((c) ^ lr) & 127) * 4])      = a##i##lo; \
    *reinterpret_cast<float4*>(&smemA[lr * 512 + (((64 + c) ^ lr) & 127) * 4]) = a##i##hi; }

#define L3PASS(p) { \
    if ((pg >> 1) == (p)) { \
        const int lrb = (pg & 1) * 8; \
        L3ST(0) L3ST(1) L3ST(2) L3ST(3) L3ST(4) L3ST(5) L3ST(6) L3ST(7) \
    } \
    __syncthreads(); \
    { \
        float q0 = 0.f, q1 = 0.f, q2 = 0.f, q3 = 0.f; \
        _Pragma("unroll 8") \
        for (int qq = 0; qq < 128; qq += 4) { \
            const float4 h0v = *reinterpret_cast<const float4*>(&smemA[m * 512 + (((qq+0) ^ m) & 127) * 4]); \
            const float4 h1v = *reinterpret_cast<const float4*>(&smemA[m * 512 + (((qq+1) ^ m) & 127) * 4]); \
            const float4 h2v = *reinterpret_cast<const float4*>(&smemA[m * 512 + (((qq+2) ^ m) & 127) * 4]); \
            const float4 h3v = *reinterpret_cast<const float4*>(&smemA[m * 512 + (((qq+3) ^ m) & 127) * 4]); \
            const float4 w0 = *reinterpret_cast<const float4*>(wr + (qq+0) * 4); \
            const float4 w1 = *reinterpret_cast<const float4*>(wr + (qq+1) * 4); \
            const float4 w2 = *reinterpret_cast<const float4*>(wr + (qq+2) * 4); \
            const float4 w3 = *reinterpret_cast<const float4*>(wr + (qq+3) * 4); \
            q0 = fmaf(h0v.w,w0.w,fmaf(h0v.z,w0.z,fmaf(h0v.y,w0.y,fmaf(h0v.x,w0.x,q0)))); \
            q1 = fmaf(h1v.w,w1.w,fmaf(h1v.z,w1.z,fmaf(h1v.y,w1.y,fmaf(h1v.x,w1.x,q1)))); \
            q2 = fmaf(h2v.w,w2.w,fmaf(h2v.z,w2.z,fmaf(h2v.y,w2.y,fmaf(h2v.x,w2.x,q2)))); \
            q3 = fmaf(h3v.w,w3.w,fmaf(h3v.z,w3.z,fmaf(h3v.y,w3.y,fmaf(h3v.x,w3.x,q3)))); \
        } \
        P.table[((size_t)net * PTS + (m0 + (p) * 16 + m)) * 32 + jg] = \
            (q0 + q1) + (q2 + q3) + b3v; \
    } \
    __syncthreads(); }

    L3PASS(0)
    L3PASS(1)
    L3PASS(2)
    L3PASS(3)
}

// ---------------------------------------------------------------------------
// Kernel 2: Catmull-Rom interp + Tucker contraction — ROUND-6 VERSION VERBATIM
// (measured ~93us; LDS broadcast reads. R12's scalar-pipe s_load variant
// regressed to ~145us; R7/R10 2-sample variants spilled. Do not touch.)
// ---------------------------------------------------------------------------
#define F4MA(acc, s, rp, k) { const float4 _v = (rp)[k]; \
    acc.x = fmaf((s), _v.x, acc.x); acc.y = fmaf((s), _v.y, acc.y); \
    acc.z = fmaf((s), _v.z, acc.z); acc.w = fmaf((s), _v.w, acc.w); }

#define GROW8(Pfx, w, rp, off) \
    F4MA(Pfx##0,(w),rp,(off)+0) F4MA(Pfx##1,(w),rp,(off)+1) \
    F4MA(Pfx##2,(w),rp,(off)+2) F4MA(Pfx##3,(w),rp,(off)+3) \
    F4MA(Pfx##4,(w),rp,(off)+4) F4MA(Pfx##5,(w),rp,(off)+5) \
    F4MA(Pfx##6,(w),rp,(off)+6) F4MA(Pfx##7,(w),rp,(off)+7)

// Catmull-Rom setup: x*G is EXACT in fp32 (power-of-two scale).
#define CRSETUP(x_, iv, c0, c1, c2, c3) \
    int iv; float c0, c1, c2, c3; { \
        float xx = (x_) * (float)G; \
        int i = (int)xx; i = i < 0 ? 0 : (i > G - 1 ? G - 1 : i); iv = i; \
        float t = xx - (float)i; \
        float t2 = t * t, t3 = t2 * t; \
        c0 = fmaf(-0.5f, t3, t2) - 0.5f * t; \
        c1 = fmaf(1.5f, t3, fmaf(-2.5f, t2, 1.f)); \
        c2 = fmaf(-1.5f, t3, fmaf(2.f, t2, 0.5f * t)); \
        c3 = 0.5f * (t3 - t2); }

__global__ __attribute__((amdgpu_waves_per_eu(2, 4))) __launch_bounds__(256)
void k_ic(const float* __restrict__ table, const float* __restrict__ core,
          const float* __restrict__ x, float* __restrict__ out)
{
    __shared__ float cs[8 * 1024];   // 32 KB: 8 r-rows of C per round
    __shared__ float red[256];

    const int tid = threadIdx.x;
    const int ls  = tid & 63;        // local sample
    const int rh  = tid >> 6;        // 0..3, wave-uniform; r = rb*8+rh*2+{0,1}
    const int g   = blockIdx.x * 64 + ls;

    const float xu = x[(size_t)g * 3 + 0];
    const float xv = x[(size_t)g * 3 + 1];
    const float xw = x[(size_t)g * 3 + 2];

#define DECLZ(Pn) float4 Pn = make_float4(0.f,0.f,0.f,0.f);
    DECLZ(W0) DECLZ(W1) DECLZ(W2) DECLZ(W3) DECLZ(W4) DECLZ(W5) DECLZ(W6) DECLZ(W7)
    DECLZ(V0) DECLZ(V1) DECLZ(V2) DECLZ(V3) DECLZ(V4) DECLZ(V5) DECLZ(V6) DECLZ(V7)
    float2 U0, U1, U2, U3;

    {   // W net (index 2)
        CRSETUP(xw, iw, c0, c1, c2, c3)
        const float4* rp = reinterpret_cast<const float4*>(
            table + ((size_t)2 * PTS + iw) * 32);
        GROW8(W, c0, rp, 0) GROW8(W, c1, rp, 8) GROW8(W, c2, rp, 16) GROW8(W, c3, rp, 24)
    }
    {   // V net (index 1)
        CRSETUP(xv, iv2, c0, c1, c2, c3)
        const float4* rp = reinterpret_cast<const float4*>(
            table + ((size_t)1 * PTS + iv2) * 32);
        GROW8(V, c0, rp, 0) GROW8(V, c1, rp, 8) GROW8(V, c2, rp, 16) GROW8(V, c3, rp, 24)
    }
    {   // U net (index 0): this thread's 8 r-cols = rb*8 + rh*2 + {0,1}
        CRSETUP(xu, iu, c0, c1, c2, c3)
        const float2* up = reinterpret_cast<const float2*>(table + (size_t)iu * 32);
#define UROW(rbv, dst) { \
        const float2 t0 = up[0 * 16 + (rbv) * 4 + rh]; \
        const float2 t1 = up[1 * 16 + (rbv) * 4 + rh]; \
        const float2 t2 = up[2 * 16 + (rbv) * 4 + rh]; \
        const float2 t3 = up[3 * 16 + (rbv) * 4 + rh]; \
        dst.x = fmaf(c0,t0.x,fmaf(c1,t1.x,fmaf(c2,t2.x,c3*t3.x))); \
        dst.y = fmaf(c0,t0.y,fmaf(c1,t1.y,fmaf(c2,t2.y,c3*t3.y))); }
        UROW(0, U0) UROW(1, U1) UROW(2, U2) UROW(3, U3)
    }

#define TQC(rl, s, tq, Wv) { \
    const float4 c4 = *reinterpret_cast<const float4*>( \
        &cs[(rh * 2 + (rl)) * 1024 + (s) * 32 + (tq) * 4]); \
    aa = fmaf(Wv.w, c4.w, fmaf(Wv.z, c4.z, fmaf(Wv.y, c4.y, fmaf(Wv.x, c4.x, aa)))); }

#define SONE(rl, s, vcomp) { float aa = 0.f; \
    TQC(rl, s, 0, W0) TQC(rl, s, 1, W1) TQC(rl, s, 2, W2) TQC(rl, s, 3, W3) \
    TQC(rl, s, 4, W4) TQC(rl, s, 5, W5) TQC(rl, s, 6, W6) TQC(rl, s, 7, W7) \
    tracc = fmaf(vcomp, aa, tracc); }

#define SG(rl, sb, Vv) \
    SONE(rl, 4*(sb)+0, Vv.x) SONE(rl, 4*(sb)+1, Vv.y) \
    SONE(rl, 4*(sb)+2, Vv.z) SONE(rl, 4*(sb)+3, Vv.w)

#define RL1(rl, ucomp) { float tracc = 0.f; \
    SG(rl, 0, V0) SG(rl, 1, V1) SG(rl, 2, V2) SG(rl, 3, V3) \
    SG(rl, 4, V4) SG(rl, 5, V5) SG(rl, 6, V6) SG(rl, 7, V7) \
    o = fmaf(ucomp, tracc, o); }

#define RBLOCK(rb) { \
    __syncthreads(); \
    _Pragma("unroll") \
    for (int cc = 0; cc < 8; ++cc) \
        *reinterpret_cast<float4*>(&cs[cc * 1024 + tid * 4]) = \
            *reinterpret_cast<const float4*>(core + (size_t)((rb) * 8 + cc) * 1024 + tid * 4); \
    __syncthreads(); \
    RL1(0, U##rb.x) RL1(1, U##rb.y) }

    float o = 0.f;
    RBLOCK(0) RBLOCK(1) RBLOCK(2) RBLOCK(3)

    red[tid] = o;
    __syncthreads();
    if (tid < 64)
        out[blockIdx.x * 64 + tid] =
            red[tid] + red[tid + 64] + red[tid + 128] + red[tid + 192];
}

// ---------------------------------------------------------------------------
extern "C" void kernel_launch(void* const* d_in, const int* in_sizes, int n_in,
                              void* d_out, int out_size, void* d_ws, size_t ws_size,
                              hipStream_t stream)
{
    AllP P;
    for (int net = 0; net < 3; ++net) {
        const int b = 1 + net * 6;
        P.n[net].w1 = (const float*)d_in[b + 0];
        P.n[net].b1 = (const float*)d_in[b + 1];
        P.n[net].w2 = (const float*)d_in[b + 2];
        P.n[net].b2 = (const float*)d_in[b + 3];
        P.n[net].w3 = (const float*)d_in[b + 4];
        P.n[net].b3 = (const float*)d_in[b + 5];
    }
    const float* xin  = (const float*)d_in[0];
    const float* core = (const float*)d_in[19];
    float* wsf   = (float*)d_ws;
    float* table = wsf;                            // 3*4160*32      = 1.60 MB
    float* w2t   = wsf + (size_t)3 * PTS * 32;     // 3*512*512      = 3.00 MB
    float* h1t   = w2t + (size_t)3 * MID * MID;    // 3*65*32*1024   = 25.6 MB
    P.table = table;

    k_prep <<<dim3(16, 16, 3), 256, 0, stream>>>(P, w2t);
    k_h1   <<<dim3(NBLK * NKS, 3), 256, 0, stream>>>(P, h1t);
    k_siren<<<dim3(NBLK, 3), 512, 0, stream>>>(P, w2t, h1t);
    k_ic   <<<NB / 64, 256, 0, stream>>>(table, core, xin, (float*)d_out);
}

// Round 14
// 339.149 us; speedup vs baseline: 1.0724x; 1.0048x over previous
//
#include <hip/hip_runtime.h>
#include <math.h>

#define MID 512
#define KT  16
#define NB  65536
#define G   4096
#define NBLK 65
#define PTS  4160   // 65 blocks * 64 points; table point p holds x = (p-1)/G
#define NKS  32

struct NetP { const float *w1,*b1,*w2,*b2,*w3,*b3; };
struct AllP { NetP n[3]; float* table; };

// ---------------------------------------------------------------------------
// Kernel 0a: transpose W2 (512x512) -> W2T[k][n] per net (slab contiguous).
// ---------------------------------------------------------------------------
__global__ __launch_bounds__(256)
void k_prep(AllP P, float* __restrict__ w2t)
{
    __shared__ float t[32][33];
    const int net = blockIdx.z;
    const float* src = (net == 0) ? P.n[0].w2 : (net == 1) ? P.n[1].w2 : P.n[2].w2;
    float* dst = w2t + (size_t)net * MID * MID;
    const int bx = blockIdx.x * 32, by = blockIdx.y * 32;
    const int tx = threadIdx.x & 31, ty = threadIdx.x >> 5;   // ty 0..7
    #pragma unroll
    for (int j = 0; j < 4; ++j)
        t[ty + 8 * j][tx] = src[(size_t)(by + ty + 8 * j) * MID + bx + tx];
    __syncthreads();
    #pragma unroll
    for (int j = 0; j < 4; ++j)
        dst[(size_t)(bx + ty + 8 * j) * MID + by + tx] = t[tx][ty + 8 * j];
}

// ---------------------------------------------------------------------------
// Kernel 0b: precompute h1 = sin(sin(4*(x*w1+b1))) in k_siren slab order:
// h1t[net][blk][ks][kt*64+m], 1024 floats per (blk,ks).
// ---------------------------------------------------------------------------
__global__ __launch_bounds__(256)
void k_h1(AllP P, float* __restrict__ h1t)
{
    const int net = blockIdx.y;
    const NetP np = (net == 0) ? P.n[0] : (net == 1) ? P.n[1] : P.n[2];
    const int bid = blockIdx.x;            // 0..NBLK*NKS-1
    const int blk = bid >> 5, ks = bid & 31;
    float* dst = h1t + ((size_t)(net * NBLK + blk) * NKS + ks) * 1024;
    #pragma unroll
    for (int r = 0; r < 4; ++r) {
        const int idx = threadIdx.x + r * 256;   // = kt*64 + m
        const int kt = idx >> 6, m = idx & 63;
        const int k = ks * 16 + kt;
        const float xv = ((float)(blk * 64 + m) - 1.0f) * (1.0f / (float)G);
        const float z = 4.f * fmaf(xv, np.w1[k], np.b1[k]);
        dst[idx] = sinf(sinf(z));
    }
}

// ---------------------------------------------------------------------------
// Kernel 1: fused SIREN, 512 threads (8 waves) x 64 points/block, 195 blocks
// (<=1 block/CU). P=8 x C=8 register tile: per kt, 2 broadcast h-reads +
// 2 strided W-reads feed 64 FMAs (half the W-reads/FMA of the R9 P=4 shape).
// waves_per_eu(2,2): R13 ran this EXACT structure under (2,8) and the
// allocator capped VGPR at 128 (4-waves/EU heuristic) -> 68MB scratch spill,
// 233us. Live set ~140 VGPR needs the 256 budget; at 1 block/CU we only get
// 2 waves/SIMD anyway, so max=2 costs nothing.
// ---------------------------------------------------------------------------
__global__ __attribute__((amdgpu_waves_per_eu(2, 2))) __launch_bounds__(512)
void k_siren(AllP P, const float* __restrict__ w2t, const float* __restrict__ h1t)
{
    __shared__ float smemA[KT * MID];   // 32 KB: W2T slab [kt][n] / layer3 h2
    __shared__ float hlds[KT * 64];     // 4 KB: h1 slab [kt][m]

    const int tid = threadIdx.x;        // 0..511
    const int net = blockIdx.y;
    const int m0  = blockIdx.x * 64;
    NetP np;
    if (net == 0)      np = P.n[0];
    else if (net == 1) np = P.n[1];
    else               np = P.n[2];
    const float* wslab  = w2t + (size_t)net * MID * MID;
    const float* h1base = h1t + ((size_t)(net * NBLK + blockIdx.x) * NKS) * 1024;

    const int c  = tid & 63;
    const int pg = tid >> 6;    // wave id 0..7 -> points pg*8 .. pg*8+7

#define ACC_DECL(i) float4 a##i##lo = make_float4(0.f,0.f,0.f,0.f); \
                    float4 a##i##hi = make_float4(0.f,0.f,0.f,0.f);
    ACC_DECL(0) ACC_DECL(1) ACC_DECL(2) ACC_DECL(3)
    ACC_DECL(4) ACC_DECL(5) ACC_DECL(6) ACC_DECL(7)

#define FMA8(i, hv) \
        a##i##lo.x = fmaf(hv, wa.x, a##i##lo.x); a##i##lo.y = fmaf(hv, wa.y, a##i##lo.y); \
        a##i##lo.z = fmaf(hv, wa.z, a##i##lo.z); a##i##lo.w = fmaf(hv, wa.w, a##i##lo.w); \
        a##i##hi.x = fmaf(hv, wb.x, a##i##hi.x); a##i##hi.y = fmaf(hv, wb.y, a##i##hi.y); \
        a##i##hi.z = fmaf(hv, wb.z, a##i##hi.z); a##i##hi.w = fmaf(hv, wb.w, a##i##hi.w);

    // prefetch: W slab f4 #(j*512 + tid), j=0..3, + 2 h floats
    float4 r0, r1, r2, r3;
    float  h0, h1;
    {
        const float* s0 = wslab + tid * 4;
        r0 = *reinterpret_cast<const float4*>(s0 + 0 * 2048);
        r1 = *reinterpret_cast<const float4*>(s0 + 1 * 2048);
        r2 = *reinterpret_cast<const float4*>(s0 + 2 * 2048);
        r3 = *reinterpret_cast<const float4*>(s0 + 3 * 2048);
        h0 = h1base[tid];
        h1 = h1base[tid + 512];
    }

    for (int ks = 0; ks < MID / KT; ++ks) {
        __syncthreads();   // (A) all waves done READING previous slab
        {   // write slab ks from prefetch regs (16B/lane contiguous, 0-conflict)
            float* d0 = &smemA[tid * 4];
            *reinterpret_cast<float4*>(d0 + 0 * 2048) = r0;
            *reinterpret_cast<float4*>(d0 + 1 * 2048) = r1;
            *reinterpret_cast<float4*>(d0 + 2 * 2048) = r2;
            *reinterpret_cast<float4*>(d0 + 3 * 2048) = r3;
            hlds[tid]       = h0;   // slab order [kt*64+m] by construction
            hlds[tid + 512] = h1;
        }
        __syncthreads();   // (B) slab ks visible

        if (ks + 1 < MID / KT) {   // issue loads for slab ks+1 (consumed next (A))
            const float* s1 = wslab + (size_t)(ks + 1) * KT * MID + tid * 4;
            r0 = *reinterpret_cast<const float4*>(s1 + 0 * 2048);
            r1 = *reinterpret_cast<const float4*>(s1 + 1 * 2048);
            r2 = *reinterpret_cast<const float4*>(s1 + 2 * 2048);
            r3 = *reinterpret_cast<const float4*>(s1 + 3 * 2048);
            h0 = h1base[(ks + 1) * 1024 + tid];
            h1 = h1base[(ks + 1) * 1024 + tid + 512];
        }

        #pragma unroll
        for (int kt = 0; kt < KT; ++kt) {
            const float4 hA = *reinterpret_cast<const float4*>(&hlds[kt * 64 + pg * 8]);
            const float4 hB = *reinterpret_cast<const float4*>(&hlds[kt * 64 + pg * 8 + 4]);
            const float4 wa = *reinterpret_cast<const float4*>(&smemA[kt * MID + c * 4]);
            const float4 wb = *reinterpret_cast<const float4*>(&smemA[kt * MID + 256 + c * 4]);
            FMA8(0, hA.x) FMA8(1, hA.y) FMA8(2, hA.z) FMA8(3, hA.w)
            FMA8(4, hB.x) FMA8(5, hB.y) FMA8(6, hB.z) FMA8(7, hB.w)
        }
    }
    __syncthreads();

    {   // epilogue: h2 = sin(sin(4*(z + b2)))
        const float4 ba = *reinterpret_cast<const float4*>(np.b2 + c * 4);
        const float4 bb = *reinterpret_cast<const float4*>(np.b2 + 256 + c * 4);
#define SS1(v, b) v = sinf(sinf(4.f * ((v) + (b))));
#define SSROW(i) \
        SS1(a##i##lo.x, ba.x) SS1(a##i##lo.y, ba.y) SS1(a##i##lo.z, ba.z) SS1(a##i##lo.w, ba.w) \
        SS1(a##i##hi.x, bb.x) SS1(a##i##hi.y, bb.y) SS1(a##i##hi.z, bb.z) SS1(a##i##hi.w, bb.w)
        SSROW(0) SSROW(1) SSROW(2) SSROW(3) SSROW(4) SSROW(5) SSROW(6) SSROW(7)
    }

    // layer 3: four 16-point passes. Pass p covers points p*16..p*16+15
    // (owner waves pg = 2p, 2p+1). XOR-swizzled smemA:
    // phys f4 (lr, n4) = lr*128 + ((n4 ^ lr) & 127), lr = local row 0..15.
    const int m  = tid & 15;    // local point
    const int jg = tid >> 4;    // 0..31 -> output col jg
    const float* wr = np.w3 + (size_t)jg * MID;
    const float  b3v = np.b3[jg];

#define L3ST(i) { const int lr = lrb + (i); \
    *reinterpret_cast<float4*>(&smemA[lr * 512 + (((c) ^ lr) & 127) * 4])      = a##i##lo; \
    *reinterpret_cast<float4*>(&smemA[lr * 512 + (((64 + c) ^ lr) & 127) * 4]) = a##i##hi; }

#define L3PASS(p) { \
    if ((pg >> 1) == (p)) { \
        const int lrb = (pg & 1) * 8; \
        L3ST(0) L3ST(1) L3ST(2) L3ST(3) L3ST(4) L3ST(5) L3ST(6) L3ST(7) \
    } \
    __syncthreads(); \
    { \
        float q0 = 0.f, q1 = 0.f, q2 = 0.f, q3 = 0.f; \
        _Pragma("unroll 8") \
        for (int qq = 0; qq < 128; qq += 4) { \
            const float4 h0v = *reinterpret_cast<const float4*>(&smemA[m * 512 + (((qq+0) ^ m) & 127) * 4]); \
            const float4 h1v = *reinterpret_cast<const float4*>(&smemA[m * 512 + (((qq+1) ^ m) & 127) * 4]); \
            const float4 h2v = *reinterpret_cast<const float4*>(&smemA[m * 512 + (((qq+2) ^ m) & 127) * 4]); \
            const float4 h3v = *reinterpret_cast<const float4*>(&smemA[m * 512 + (((qq+3) ^ m) & 127) * 4]); \
            const float4 w0 = *reinterpret_cast<const float4*>(wr + (qq+0) * 4); \
            const float4 w1 = *reinterpret_cast<const float4*>(wr + (qq+1) * 4); \
            const float4 w2 = *reinterpret_cast<const float4*>(wr + (qq+2) * 4); \
            const float4 w3 = *reinterpret_cast<const float4*>(wr + (qq+3) * 4); \
            q0 = fmaf(h0v.w,w0.w,fmaf(h0v.z,w0.z,fmaf(h0v.y,w0.y,fmaf(h0v.x,w0.x,q0)))); \
            q1 = fmaf(h1v.w,w1.w,fmaf(h1v.z,w1.z,fmaf(h1v.y,w1.y,fmaf(h1v.x,w1.x,q1)))); \
            q2 = fmaf(h2v.w,w2.w,fmaf(h2v.z,w2.z,fmaf(h2v.y,w2.y,fmaf(h2v.x,w2.x,q2)))); \
            q3 = fmaf(h3v.w,w3.w,fmaf(h3v.z,w3.z,fmaf(h3v.y,w3.y,fmaf(h3v.x,w3.x,q3)))); \
        } \
        P.table[((size_t)net * PTS + (m0 + (p) * 16 + m)) * 32 + jg] = \
            (q0 + q1) + (q2 + q3) + b3v; \
    } \
    __syncthreads(); }

    L3PASS(0)
    L3PASS(1)
    L3PASS(2)
    L3PASS(3)
}

// ---------------------------------------------------------------------------
// Kernel 2: Catmull-Rom interp + Tucker contraction — ROUND-6 VERSION VERBATIM
// (measured ~93us; LDS broadcast reads. R12's scalar-pipe s_load variant
// regressed to ~145us; R7/R10 2-sample variants spilled. Do not touch.)
// ---------------------------------------------------------------------------
#define F4MA(acc, s, rp, k) { const float4 _v = (rp)[k]; \
    acc.x = fmaf((s), _v.x, acc.x); acc.y = fmaf((s), _v.y, acc.y); \
    acc.z = fmaf((s), _v.z, acc.z); acc.w = fmaf((s), _v.w, acc.w); }

#define GROW8(Pfx, w, rp, off) \
    F4MA(Pfx##0,(w),rp,(off)+0) F4MA(Pfx##1,(w),rp,(off)+1) \
    F4MA(Pfx##2,(w),rp,(off)+2) F4MA(Pfx##3,(w),rp,(off)+3) \
    F4MA(Pfx##4,(w),rp,(off)+4) F4MA(Pfx##5,(w),rp,(off)+5) \
    F4MA(Pfx##6,(w),rp,(off)+6) F4MA(Pfx##7,(w),rp,(off)+7)

// Catmull-Rom setup: x*G is EXACT in fp32 (power-of-two scale).
#define CRSETUP(x_, iv, c0, c1, c2, c3) \
    int iv; float c0, c1, c2, c3; { \
        float xx = (x_) * (float)G; \
        int i = (int)xx; i = i < 0 ? 0 : (i > G - 1 ? G - 1 : i); iv = i; \
        float t = xx - (float)i; \
        float t2 = t * t, t3 = t2 * t; \
        c0 = fmaf(-0.5f, t3, t2) - 0.5f * t; \
        c1 = fmaf(1.5f, t3, fmaf(-2.5f, t2, 1.f)); \
        c2 = fmaf(-1.5f, t3, fmaf(2.f, t2, 0.5f * t)); \
        c3 = 0.5f * (t3 - t2); }

__global__ __attribute__((amdgpu_waves_per_eu(2, 4))) __launch_bounds__(256)
void k_ic(const float* __restrict__ table, const float* __restrict__ core,
          const float* __restrict__ x, float* __restrict__ out)
{
    __shared__ float cs[8 * 1024];   // 32 KB: 8 r-rows of C per round
    __shared__ float red[256];

    const int tid = threadIdx.x;
    const int ls  = tid & 63;        // local sample
    const int rh  = tid >> 6;        // 0..3, wave-uniform; r = rb*8+rh*2+{0,1}
    const int g   = blockIdx.x * 64 + ls;

    const float xu = x[(size_t)g * 3 + 0];
    const float xv = x[(size_t)g * 3 + 1];
    const float xw = x[(size_t)g * 3 + 2];

#define DECLZ(Pn) float4 Pn = make_float4(0.f,0.f,0.f,0.f);
    DECLZ(W0) DECLZ(W1) DECLZ(W2) DECLZ(W3) DECLZ(W4) DECLZ(W5) DECLZ(W6) DECLZ(W7)
    DECLZ(V0) DECLZ(V1) DECLZ(V2) DECLZ(V3) DECLZ(V4) DECLZ(V5) DECLZ(V6) DECLZ(V7)
    float2 U0, U1, U2, U3;

    {   // W net (index 2)
        CRSETUP(xw, iw, c0, c1, c2, c3)
        const float4* rp = reinterpret_cast<const float4*>(
            table + ((size_t)2 * PTS + iw) * 32);
        GROW8(W, c0, rp, 0) GROW8(W, c1, rp, 8) GROW8(W, c2, rp, 16) GROW8(W, c3, rp, 24)
    }
    {   // V net (index 1)
        CRSETUP(xv, iv2, c0, c1, c2, c3)
        const float4* rp = reinterpret_cast<const float4*>(
            table + ((size_t)1 * PTS + iv2) * 32);
        GROW8(V, c0, rp, 0) GROW8(V, c1, rp, 8) GROW8(V, c2, rp, 16) GROW8(V, c3, rp, 24)
    }
    {   // U net (index 0): this thread's 8 r-cols = rb*8 + rh*2 + {0,1}
        CRSETUP(xu, iu, c0, c1, c2, c3)
        const float2* up = reinterpret_cast<const float2*>(table + (size_t)iu * 32);
#define UROW(rbv, dst) { \
        const float2 t0 = up[0 * 16 + (rbv) * 4 + rh]; \
        const float2 t1 = up[1 * 16 + (rbv) * 4 + rh]; \
        const float2 t2 = up[2 * 16 + (rbv) * 4 + rh]; \
        const float2 t3 = up[3 * 16 + (rbv) * 4 + rh]; \
        dst.x = fmaf(c0,t0.x,fmaf(c1,t1.x,fmaf(c2,t2.x,c3*t3.x))); \
        dst.y = fmaf(c0,t0.y,fmaf(c1,t1.y,fmaf(c2,t2.y,c3*t3.y))); }
        UROW(0, U0) UROW(1, U1) UROW(2, U2) UROW(3, U3)
    }

#define TQC(rl, s, tq, Wv) { \
    const float4 c4 = *reinterpret_cast<const float4*>( \
        &cs[(rh * 2 + (rl)) * 1024 + (s) * 32 + (tq) * 4]); \
    aa = fmaf(Wv.w, c4.w, fmaf(Wv.z, c4.z, fmaf(Wv.y, c4.y, fmaf(Wv.x, c4.x, aa)))); }

#define SONE(rl, s, vcomp) { float aa = 0.f; \
    TQC(rl, s, 0, W0) TQC(rl, s, 1, W1) TQC(rl, s, 2, W2) TQC(rl, s, 3, W3) \
    TQC(rl, s, 4, W4) TQC(rl, s, 5, W5) TQC(rl, s, 6, W6) TQC(rl, s, 7, W7) \
    tracc = fmaf(vcomp, aa, tracc); }

#define SG(rl, sb, Vv) \
    SONE(rl, 4*(sb)+0, Vv.x) SONE(rl, 4*(sb)+1, Vv.y) \
    SONE(rl, 4*(sb)+2, Vv.z) SONE(rl, 4*(sb)+3, Vv.w)

#define RL1(rl, ucomp) { float tracc = 0.f; \
    SG(rl, 0, V0) SG(rl, 1, V1) SG(rl, 2, V2) SG(rl, 3, V3) \
    SG(rl, 4, V4) SG(rl, 5, V5) SG(rl, 6, V6) SG(rl, 7, V7) \
    o = fmaf(ucomp, tracc, o); }

#define RBLOCK(rb) { \
    __syncthreads(); \
    _Pragma("unroll") \
    for (int cc = 0; cc < 8; ++cc) \
        *reinterpret_cast<float4*>(&cs[cc * 1024 + tid * 4]) = \
            *reinterpret_cast<const float4*>(core + (size_t)((rb) * 8 + cc) * 1024 + tid * 4); \
    __syncthreads(); \
    RL1(0, U##rb.x) RL1(1, U##rb.y) }

    float o = 0.f;
    RBLOCK(0) RBLOCK(1) RBLOCK(2) RBLOCK(3)

    red[tid] = o;
    __syncthreads();
    if (tid < 64)
        out[blockIdx.x * 64 + tid] =
            red[tid] + red[tid + 64] + red[tid + 128] + red[tid + 192];
}

// ---------------------------------------------------------------------------
extern "C" void kernel_launch(void* const* d_in, const int* in_sizes, int n_in,
                              void* d_out, int out_size, void* d_ws, size_t ws_size,
                              hipStream_t stream)
{
    AllP P;
    for (int net = 0; net < 3; ++net) {
        const int b = 1 + net * 6;
        P.n[net].w1 = (const float*)d_in[b + 0];
        P.n[net].b1 = (const float*)d_in[b + 1];
        P.n[net].w2 = (const float*)d_in[b + 2];
        P.n[net].b2 = (const float*)d_in[b + 3];
        P.n[net].w3 = (const float*)d_in[b + 4];
        P.n[net].b3 = (const float*)d_in[b + 5];
    }
    const float* xin  = (const float*)d_in[0];
    const float* core = (const float*)d_in[19];
    float* wsf   = (float*)d_ws;
    float* table = wsf;                            // 3*4160*32      = 1.60 MB
    float* w2t   = wsf + (size_t)3 * PTS * 32;     // 3*512*512      = 3.00 MB
    float* h1t   = w2t + (size_t)3 * MID * MID;    // 3*65*32*1024   = 25.6 MB
    P.table = table;

    k_prep <<<dim3(16, 16, 3), 256, 0, stream>>>(P, w2t);
    k_h1   <<<dim3(NBLK * NKS, 3), 256, 0, stream>>>(P, h1t);
    k_siren<<<dim3(NBLK, 3), 512, 0, stream>>>(P, w2t, h1t);
    k_ic   <<<NB / 64, 256, 0, stream>>>(table, core, xin, (float*)d_out);
}

// Round 15
// 300.090 us; speedup vs baseline: 1.2120x; 1.1302x over previous
//
#include <hip/hip_runtime.h>
#include <math.h>

#define MID 512
#define KT  16
#define NB  65536
#define G   4096
#define NBLK 258
#define PTS  4128   // 258 blocks * 16 points; table point p holds x = (p-1)/G
#define NKS  32

struct NetP { const float *w1,*b1,*w2,*b2,*w3,*b3; };
struct AllP { NetP n[3]; float* table; };

// ---------------------------------------------------------------------------
// Kernel 0a: transpose W2 (512x512) -> W2T[k][n] per net (slab contiguous).
// ---------------------------------------------------------------------------
__global__ __launch_bounds__(256)
void k_prep(AllP P, float* __restrict__ w2t)
{
    __shared__ float t[32][33];
    const int net = blockIdx.z;
    const float* src = (net == 0) ? P.n[0].w2 : (net == 1) ? P.n[1].w2 : P.n[2].w2;
    float* dst = w2t + (size_t)net * MID * MID;
    const int bx = blockIdx.x * 32, by = blockIdx.y * 32;
    const int tx = threadIdx.x & 31, ty = threadIdx.x >> 5;   // ty 0..7
    #pragma unroll
    for (int j = 0; j < 4; ++j)
        t[ty + 8 * j][tx] = src[(size_t)(by + ty + 8 * j) * MID + bx + tx];
    __syncthreads();
    #pragma unroll
    for (int j = 0; j < 4; ++j)
        dst[(size_t)(bx + ty + 8 * j) * MID + by + tx] = t[tx][ty + 8 * j];
}

// ---------------------------------------------------------------------------
// Kernel 0b: precompute h1 = sin(sin(4*(x*w1+b1))) in k_siren slab order:
// h1t[net][blk][ks][kt*16+m], 256 floats per (blk,ks).
// ---------------------------------------------------------------------------
__global__ __launch_bounds__(256)
void k_h1(AllP P, float* __restrict__ h1t)
{
    const int net = blockIdx.y;
    const NetP np = (net == 0) ? P.n[0] : (net == 1) ? P.n[1] : P.n[2];
    const int bid = blockIdx.x;            // 0..NBLK*NKS-1: blk = bid>>5, ks = bid&31
    const int tid = threadIdx.x;           // kt = tid>>4, m = tid&15
    const int blk = bid >> 5, ks = bid & 31;
    const int kt = tid >> 4,  m  = tid & 15;
    const int k = ks * 16 + kt;
    const float xv = ((float)(blk * 16 + m) - 1.0f) * (1.0f / (float)G);
    const float z = 4.f * fmaf(xv, np.w1[k], np.b1[k]);
    h1t[((size_t)net * (NBLK * NKS) + bid) * 256 + tid] = sinf(sinf(z));
}

// ---------------------------------------------------------------------------
// Kernel 1: fused SIREN, 256 threads (4 waves) x 16 points/block, 774 blocks
// (3.02/CU balanced). NEW TILE: P=8 points x C=4 cols per thread (32 acc
// floats — SAME register budget as R12's P=4xC=8 which ran spill-free at
// VGPR=96). Wave w = tid>>6 decomposes as (pg = w>>1: point-half, ch = w&1:
// col-half). Per kt: 2 BROADCAST h-reads + only ONE strided W-read feed 32
// FMAs (R12 issued 2 strided W-reads per 32 FMAs -> LDS pipe 1.75x
// oversubscribed, VALUBusy 41%; this cuts LDS cycles to ~1.25x).
// R13/R14 lesson: 512-thread blocks cap at 128 VGPR regardless of
// waves_per_eu -> the bigger-register route is dead; this keeps 256 threads.
// Layer 3: single pass, full 16x512 h2 in smemA, XOR swizzle.
// ---------------------------------------------------------------------------
__global__ __attribute__((amdgpu_waves_per_eu(2, 8))) __launch_bounds__(256)
void k_siren(AllP P, const float* __restrict__ w2t, const float* __restrict__ h1t)
{
    __shared__ float smemA[KT * MID];   // 32 KB: W2T slab [kt][n] / layer3 h2
    __shared__ float hlds[KT * 16];     // 1 KB: h1 slab [kt][m]

    const int tid = threadIdx.x;
    const int net = blockIdx.y;
    const int m0  = blockIdx.x * 16;
    NetP np;
    if (net == 0)      np = P.n[0];
    else if (net == 1) np = P.n[1];
    else               np = P.n[2];
    const float* wslab  = w2t + (size_t)net * MID * MID;
    const float* h1base = h1t + ((size_t)net * (NBLK * NKS) + (size_t)blockIdx.x * NKS) * 256;

    const int c  = tid & 63;
    const int w  = tid >> 6;    // wave 0..3
    const int pg = w >> 1;      // point-half: points pg*8 .. pg*8+7
    const int ch = w & 1;       // col-half:   cols ch*256 + c*4 .. +3

    // 8 named f4 accumulators: a_i = acc for point pg*8+i, cols ch*256+c*4..+3
#define ACC_DECL(i) float4 a##i = make_float4(0.f,0.f,0.f,0.f);
    ACC_DECL(0) ACC_DECL(1) ACC_DECL(2) ACC_DECL(3)
    ACC_DECL(4) ACC_DECL(5) ACC_DECL(6) ACC_DECL(7)

#define FMA4(i, hv) \
        a##i.x = fmaf(hv, wa.x, a##i.x); a##i.y = fmaf(hv, wa.y, a##i.y); \
        a##i.z = fmaf(hv, wa.z, a##i.z); a##i.w = fmaf(hv, wa.w, a##i.w);

    // prefetch: W slab f4 #(q*256 + tid), q=0..7, + 1 h float
    float4 r0, r1, r2, r3, r4, r5, r6, r7;
    float  hr;
    {
        const float* s0 = wslab + tid * 4;
        r0 = *reinterpret_cast<const float4*>(s0 + 0 * 1024);
        r1 = *reinterpret_cast<const float4*>(s0 + 1 * 1024);
        r2 = *reinterpret_cast<const float4*>(s0 + 2 * 1024);
        r3 = *reinterpret_cast<const float4*>(s0 + 3 * 1024);
        r4 = *reinterpret_cast<const float4*>(s0 + 4 * 1024);
        r5 = *reinterpret_cast<const float4*>(s0 + 5 * 1024);
        r6 = *reinterpret_cast<const float4*>(s0 + 6 * 1024);
        r7 = *reinterpret_cast<const float4*>(s0 + 7 * 1024);
        hr = h1base[tid];
    }

    for (int ks = 0; ks < MID / KT; ++ks) {
        __syncthreads();   // (A) all waves done READING previous slab
        {   // write slab ks from prefetch regs (16B/lane contiguous, 0-conflict)
            float* d0 = &smemA[tid * 4];
            *reinterpret_cast<float4*>(d0 + 0 * 1024) = r0;
            *reinterpret_cast<float4*>(d0 + 1 * 1024) = r1;
            *reinterpret_cast<float4*>(d0 + 2 * 1024) = r2;
            *reinterpret_cast<float4*>(d0 + 3 * 1024) = r3;
            *reinterpret_cast<float4*>(d0 + 4 * 1024) = r4;
            *reinterpret_cast<float4*>(d0 + 5 * 1024) = r5;
            *reinterpret_cast<float4*>(d0 + 6 * 1024) = r6;
            *reinterpret_cast<float4*>(d0 + 7 * 1024) = r7;
            hlds[tid] = hr;   // slab order [kt*16+m] by construction
        }
        __syncthreads();   // (B) slab ks visible

        if (ks + 1 < MID / KT) {   // issue loads for slab ks+1 (consumed next (A))
            const float* s1 = wslab + (size_t)(ks + 1) * KT * MID + tid * 4;
            r0 = *reinterpret_cast<const float4*>(s1 + 0 * 1024);
            r1 = *reinterpret_cast<const float4*>(s1 + 1 * 1024);
            r2 = *reinterpret_cast<const float4*>(s1 + 2 * 1024);
            r3 = *reinterpret_cast<const float4*>(s1 + 3 * 1024);
            r4 = *reinterpret_cast<const float4*>(s1 + 4 * 1024);
            r5 = *reinterpret_cast<const float4*>(s1 + 5 * 1024);
            r6 = *reinterpret_cast<const float4*>(s1 + 6 * 1024);
            r7 = *reinterpret_cast<const float4*>(s1 + 7 * 1024);
            hr = h1base[(ks + 1) * 256 + tid];
        }

        #pragma unroll
        for (int kt = 0; kt < KT; ++kt) {
            const float4 hA = *reinterpret_cast<const float4*>(&hlds[kt * 16 + pg * 8]);
            const float4 hB = *reinterpret_cast<const float4*>(&hlds[kt * 16 + pg * 8 + 4]);
            const float4 wa = *reinterpret_cast<const float4*>(
                &smemA[kt * MID + ch * 256 + c * 4]);
            FMA4(0, hA.x) FMA4(1, hA.y) FMA4(2, hA.z) FMA4(3, hA.w)
            FMA4(4, hB.x) FMA4(5, hB.y) FMA4(6, hB.z) FMA4(7, hB.w)
        }
    }
    __syncthreads();

    {   // epilogue: h2 = sin(sin(4*(z + b2))) — this thread's 4 cols
        const float4 bv = *reinterpret_cast<const float4*>(np.b2 + ch * 256 + c * 4);
#define SS1(v, b) v = sinf(sinf(4.f * ((v) + (b))));
#define SSROW(i) SS1(a##i.x, bv.x) SS1(a##i.y, bv.y) SS1(a##i.z, bv.z) SS1(a##i.w, bv.w)
        SSROW(0) SSROW(1) SSROW(2) SSROW(3) SSROW(4) SSROW(5) SSROW(6) SSROW(7)
    }

    // layer 3: single pass — full h2 (16 pts x 512 = 32KB) in smemA.
    // XOR swizzle: phys f4 (row, n4) = row*128 + ((n4 ^ row) & 127),
    // n4 = ch*64 + c. Store: row uniform/instr, n4 permutation -> 0-conflict.
    // Read: 16 lanes same qq, rows 0..15 -> 2-way on f4 = free.
    {
        const int n4 = ch * 64 + c;
#define L3ST(i) { const int rw = pg * 8 + (i); \
        *reinterpret_cast<float4*>(&smemA[rw * 512 + ((n4 ^ rw) & 127) * 4]) = a##i; }
        L3ST(0) L3ST(1) L3ST(2) L3ST(3) L3ST(4) L3ST(5) L3ST(6) L3ST(7)
    }
    __syncthreads();

    {   // m = tid&15 (point), jg = tid>>4 (0..15) -> output cols jg*2, jg*2+1
        const int m  = tid & 15;
        const int jg = tid >> 4;
        const float* wr0 = np.w3 + (size_t)(jg * 2) * MID;
        const float* wr1 = wr0 + MID;
        float p0a = 0.f, p0b = 0.f, p1a = 0.f, p1b = 0.f;
        #pragma unroll 8
        for (int qq = 0; qq < 128; ++qq) {
            const float4 h  = *reinterpret_cast<const float4*>(
                &smemA[m * 512 + ((qq ^ m) & 127) * 4]);
            const float4 w0 = *reinterpret_cast<const float4*>(wr0 + qq * 4);
            const float4 w1 = *reinterpret_cast<const float4*>(wr1 + qq * 4);
            p0a = fmaf(h.y, w0.y, fmaf(h.x, w0.x, p0a));
            p0b = fmaf(h.w, w0.w, fmaf(h.z, w0.z, p0b));
            p1a = fmaf(h.y, w1.y, fmaf(h.x, w1.x, p1a));
            p1b = fmaf(h.w, w1.w, fmaf(h.z, w1.z, p1b));
        }
        const float2 b3v = *reinterpret_cast<const float2*>(np.b3 + jg * 2);
        float2 r; r.x = p0a + p0b + b3v.x; r.y = p1a + p1b + b3v.y;
        *reinterpret_cast<float2*>(
            &P.table[((size_t)net * PTS + (m0 + m)) * 32 + jg * 2]) = r;
    }
}

// ---------------------------------------------------------------------------
// Kernel 2: Catmull-Rom interp + Tucker contraction — ROUND-6 VERSION VERBATIM
// (measured ~93us; LDS broadcast reads. R12's scalar-pipe s_load variant
// regressed to ~145us; R7/R10 2-sample variants spilled. Do not touch.)
// ---------------------------------------------------------------------------
#define F4MA(acc, s, rp, k) { const float4 _v = (rp)[k]; \
    acc.x = fmaf((s), _v.x, acc.x); acc.y = fmaf((s), _v.y, acc.y); \
    acc.z = fmaf((s), _v.z, acc.z); acc.w = fmaf((s), _v.w, acc.w); }

#define GROW8(Pfx, w, rp, off) \
    F4MA(Pfx##0,(w),rp,(off)+0) F4MA(Pfx##1,(w),rp,(off)+1) \
    F4MA(Pfx##2,(w),rp,(off)+2) F4MA(Pfx##3,(w),rp,(off)+3) \
    F4MA(Pfx##4,(w),rp,(off)+4) F4MA(Pfx##5,(w),rp,(off)+5) \
    F4MA(Pfx##6,(w),rp,(off)+6) F4MA(Pfx##7,(w),rp,(off)+7)

// Catmull-Rom setup: x*G is EXACT in fp32 (power-of-two scale).
#define CRSETUP(x_, iv, c0, c1, c2, c3) \
    int iv; float c0, c1, c2, c3; { \
        float xx = (x_) * (float)G; \
        int i = (int)xx; i = i < 0 ? 0 : (i > G - 1 ? G - 1 : i); iv = i; \
        float t = xx - (float)i; \
        float t2 = t * t, t3 = t2 * t; \
        c0 = fmaf(-0.5f, t3, t2) - 0.5f * t; \
        c1 = fmaf(1.5f, t3, fmaf(-2.5f, t2, 1.f)); \
        c2 = fmaf(-1.5f, t3, fmaf(2.f, t2, 0.5f * t)); \
        c3 = 0.5f * (t3 - t2); }

__global__ __attribute__((amdgpu_waves_per_eu(2, 4))) __launch_bounds__(256)
void k_ic(const float* __restrict__ table, const float* __restrict__ core,
          const float* __restrict__ x, float* __restrict__ out)
{
    __shared__ float cs[8 * 1024];   // 32 KB: 8 r-rows of C per round
    __shared__ float red[256];

    const int tid = threadIdx.x;
    const int ls  = tid & 63;        // local sample
    const int rh  = tid >> 6;        // 0..3, wave-uniform; r = rb*8+rh*2+{0,1}
    const int g   = blockIdx.x * 64 + ls;

    const float xu = x[(size_t)g * 3 + 0];
    const float xv = x[(size_t)g * 3 + 1];
    const float xw = x[(size_t)g * 3 + 2];

#define DECLZ(Pn) float4 Pn = make_float4(0.f,0.f,0.f,0.f);
    DECLZ(W0) DECLZ(W1) DECLZ(W2) DECLZ(W3) DECLZ(W4) DECLZ(W5) DECLZ(W6) DECLZ(W7)
    DECLZ(V0) DECLZ(V1) DECLZ(V2) DECLZ(V3) DECLZ(V4) DECLZ(V5) DECLZ(V6) DECLZ(V7)
    float2 U0, U1, U2, U3;

    {   // W net (index 2)
        CRSETUP(xw, iw, c0, c1, c2, c3)
        const float4* rp = reinterpret_cast<const float4*>(
            table + ((size_t)2 * PTS + iw) * 32);
        GROW8(W, c0, rp, 0) GROW8(W, c1, rp, 8) GROW8(W, c2, rp, 16) GROW8(W, c3, rp, 24)
    }
    {   // V net (index 1)
        CRSETUP(xv, iv2, c0, c1, c2, c3)
        const float4* rp = reinterpret_cast<const float4*>(
            table + ((size_t)1 * PTS + iv2) * 32);
        GROW8(V, c0, rp, 0) GROW8(V, c1, rp, 8) GROW8(V, c2, rp, 16) GROW8(V, c3, rp, 24)
    }
    {   // U net (index 0): this thread's 8 r-cols = rb*8 + rh*2 + {0,1}
        CRSETUP(xu, iu, c0, c1, c2, c3)
        const float2* up = reinterpret_cast<const float2*>(table + (size_t)iu * 32);
#define UROW(rbv, dst) { \
        const float2 t0 = up[0 * 16 + (rbv) * 4 + rh]; \
        const float2 t1 = up[1 * 16 + (rbv) * 4 + rh]; \
        const float2 t2 = up[2 * 16 + (rbv) * 4 + rh]; \
        const float2 t3 = up[3 * 16 + (rbv) * 4 + rh]; \
        dst.x = fmaf(c0,t0.x,fmaf(c1,t1.x,fmaf(c2,t2.x,c3*t3.x))); \
        dst.y = fmaf(c0,t0.y,fmaf(c1,t1.y,fmaf(c2,t2.y,c3*t3.y))); }
        UROW(0, U0) UROW(1, U1) UROW(2, U2) UROW(3, U3)
    }

#define TQC(rl, s, tq, Wv) { \
    const float4 c4 = *reinterpret_cast<const float4*>( \
        &cs[(rh * 2 + (rl)) * 1024 + (s) * 32 + (tq) * 4]); \
    aa = fmaf(Wv.w, c4.w, fmaf(Wv.z, c4.z, fmaf(Wv.y, c4.y, fmaf(Wv.x, c4.x, aa)))); }

#define SONE(rl, s, vcomp) { float aa = 0.f; \
    TQC(rl, s, 0, W0) TQC(rl, s, 1, W1) TQC(rl, s, 2, W2) TQC(rl, s, 3, W3) \
    TQC(rl, s, 4, W4) TQC(rl, s, 5, W5) TQC(rl, s, 6, W6) TQC(rl, s, 7, W7) \
    tracc = fmaf(vcomp, aa, tracc); }

#define SG(rl, sb, Vv) \
    SONE(rl, 4*(sb)+0, Vv.x) SONE(rl, 4*(sb)+1, Vv.y) \
    SONE(rl, 4*(sb)+2, Vv.z) SONE(rl, 4*(sb)+3, Vv.w)

#define RL1(rl, ucomp) { float tracc = 0.f; \
    SG(rl, 0, V0) SG(rl, 1, V1) SG(rl, 2, V2) SG(rl, 3, V3) \
    SG(rl, 4, V4) SG(rl, 5, V5) SG(rl, 6, V6) SG(rl, 7, V7) \
    o = fmaf(ucomp, tracc, o); }

#define RBLOCK(rb) { \
    __syncthreads(); \
    _Pragma("unroll") \
    for (int cc = 0; cc < 8; ++cc) \
        *reinterpret_cast<float4*>(&cs[cc * 1024 + tid * 4]) = \
            *reinterpret_cast<const float4*>(core + (size_t)((rb) * 8 + cc) * 1024 + tid * 4); \
    __syncthreads(); \
    RL1(0, U##rb.x) RL1(1, U##rb.y) }

    float o = 0.f;
    RBLOCK(0) RBLOCK(1) RBLOCK(2) RBLOCK(3)

    red[tid] = o;
    __syncthreads();
    if (tid < 64)
        out[blockIdx.x * 64 + tid] =
            red[tid] + red[tid + 64] + red[tid + 128] + red[tid + 192];
}

// ---------------------------------------------------------------------------
extern "C" void kernel_launch(void* const* d_in, const int* in_sizes, int n_in,
                              void* d_out, int out_size, void* d_ws, size_t ws_size,
                              hipStream_t stream)
{
    AllP P;
    for (int net = 0; net < 3; ++net) {
        const int b = 1 + net * 6;
        P.n[net].w1 = (const float*)d_in[b + 0];
        P.n[net].b1 = (const float*)d_in[b + 1];
        P.n[net].w2 = (const float*)d_in[b + 2];
        P.n[net].b2 = (const float*)d_in[b + 3];
        P.n[net].w3 = (const float*)d_in[b + 4];
        P.n[net].b3 = (const float*)d_in[b + 5];
    }
    const float* xin  = (const float*)d_in[0];
    const float* core = (const float*)d_in[19];
    float* wsf   = (float*)d_ws;
    float* table = wsf;                            // 3*4128*32     = 1.58 MB
    float* w2t   = wsf + (size_t)3 * PTS * 32;     // 3*512*512     = 3.00 MB
    float* h1t   = w2t + (size_t)3 * MID * MID;    // 3*8256*256    = 25.4 MB
    P.table = table;

    k_prep <<<dim3(16, 16, 3), 256, 0, stream>>>(P, w2t);
    k_h1   <<<dim3(NBLK * NKS, 3), 256, 0, stream>>>(P, h1t);
    k_siren<<<dim3(NBLK, 3), 256, 0, stream>>>(P, w2t, h1t);
    k_ic   <<<NB / 64, 256, 0, stream>>>(table, core, xin, (float*)d_out);
}

// Round 16
// 269.653 us; speedup vs baseline: 1.3488x; 1.1129x over previous
//
#include <hip/hip_runtime.h>
#include <math.h>

#define MID 512
#define NB  65536
#define G   4096
#define NBLK 258
#define PTS  4128   // 258 blocks * 16 points; table point p holds x = (p-1)/G

struct NetP { const float *w1,*b1,*w2,*b2,*w3,*b3; };
struct AllP { NetP n[3]; float* table; };

// ---------------------------------------------------------------------------
// Kernel 0: transpose W2 (512x512) -> W2T[k][n] per net.
// ---------------------------------------------------------------------------
__global__ __launch_bounds__(256)
void k_prep(AllP P, float* __restrict__ w2t)
{
    __shared__ float t[32][33];
    const int net = blockIdx.z;
    const float* src = (net == 0) ? P.n[0].w2 : (net == 1) ? P.n[1].w2 : P.n[2].w2;
    float* dst = w2t + (size_t)net * MID * MID;
    const int bx = blockIdx.x * 32, by = blockIdx.y * 32;
    const int tx = threadIdx.x & 31, ty = threadIdx.x >> 5;   // ty 0..7
    #pragma unroll
    for (int j = 0; j < 4; ++j)
        t[ty + 8 * j][tx] = src[(size_t)(by + ty + 8 * j) * MID + bx + tx];
    __syncthreads();
    #pragma unroll
    for (int j = 0; j < 4; ++j)
        dst[(size_t)(bx + ty + 8 * j) * MID + by + tx] = t[tx][ty + 8 * j];
}

// ---------------------------------------------------------------------------
// Kernel 1: fused SIREN, 256 threads x 16 points/block, 774 blocks (3.02/CU).
// NO LDS STAGING, NO K-LOOP BARRIERS: W2T is read directly from L2 (1MB/net,
// L2-resident, each wave reads one coalesced 1KB row segment per k). h1 for
// the block's 16 points is computed ONCE into a 32KB LDS buffer ([512][16]);
// per k the K-loop does 2 wave-uniform broadcast b128 reads + 1 global b128
// + 32 FMAs per thread. R9-R15 showed the barrier-staged structure was stuck
// at ~190us regardless of LDS-read count; this removes the structure.
// Tile: P=8 points x C=4 cols/thread (32 acc floats, proven VGPR~100).
// Layer 3: single pass through the same 32KB buffer, XOR swizzle (R15).
// ---------------------------------------------------------------------------
__global__ __attribute__((amdgpu_waves_per_eu(2, 8))) __launch_bounds__(256)
void k_siren(AllP P, const float* __restrict__ w2t)
{
    __shared__ float sbuf[MID * 16];    // 32 KB: h1 [k][m] during loop; h2 after

    const int tid = threadIdx.x;
    const int net = blockIdx.y;
    const int m0  = blockIdx.x * 16;
    NetP np;
    if (net == 0)      np = P.n[0];
    else if (net == 1) np = P.n[1];
    else               np = P.n[2];
    const float* wslab = w2t + (size_t)net * MID * MID;

    const int c  = tid & 63;
    const int w  = tid >> 6;    // wave 0..3
    const int pg = w >> 1;      // point-half: points pg*8 .. pg*8+7
    const int ch = w & 1;       // col-half:   cols ch*256 + c*4 .. +3

    // ---- fill h1[k][m] = sin(sin(4*(x_m*w1[k]+b1[k]))), 32 entries/thread
    {
        const float invG = 1.0f / (float)G;
        for (int j = 0; j < 32; ++j) {
            const int idx = tid + j * 256;        // = k*16 + m
            const int k = idx >> 4, m = idx & 15;
            const float xv = ((float)(m0 + m) - 1.0f) * invG;
            const float z = 4.f * fmaf(xv, np.w1[k], np.b1[k]);
            sbuf[idx] = sinf(sinf(z));
        }
    }
    __syncthreads();

#define ACC_DECL(i) float4 a##i = make_float4(0.f,0.f,0.f,0.f);
    ACC_DECL(0) ACC_DECL(1) ACC_DECL(2) ACC_DECL(3)
    ACC_DECL(4) ACC_DECL(5) ACC_DECL(6) ACC_DECL(7)

#define FMA4(i, hv) \
        a##i.x = fmaf(hv, wa.x, a##i.x); a##i.y = fmaf(hv, wa.y, a##i.y); \
        a##i.z = fmaf(hv, wa.z, a##i.z); a##i.w = fmaf(hv, wa.w, a##i.w);

    // ---- K loop: barrier-free. 1 global b128 (W row segment, L2-hit) +
    //      2 broadcast LDS b128 (h) feed 32 FMAs per thread per k.
    {
        const float* wp = wslab + ch * 256 + c * 4;
        const float* hp = &sbuf[pg * 8];
        #pragma unroll 8
        for (int k = 0; k < MID; ++k) {
            const float4 wa = *reinterpret_cast<const float4*>(wp + (size_t)k * MID);
            const float4 hA = *reinterpret_cast<const float4*>(hp + k * 16);
            const float4 hB = *reinterpret_cast<const float4*>(hp + k * 16 + 4);
            FMA4(0, hA.x) FMA4(1, hA.y) FMA4(2, hA.z) FMA4(3, hA.w)
            FMA4(4, hB.x) FMA4(5, hB.y) FMA4(6, hB.z) FMA4(7, hB.w)
        }
    }
    __syncthreads();   // h1 no longer needed; sbuf becomes the h2 buffer

    {   // epilogue: h2 = sin(sin(4*(z + b2))) — this thread's 4 cols
        const float4 bv = *reinterpret_cast<const float4*>(np.b2 + ch * 256 + c * 4);
#define SS1(v, b) v = sinf(sinf(4.f * ((v) + (b))));
#define SSROW(i) SS1(a##i.x, bv.x) SS1(a##i.y, bv.y) SS1(a##i.z, bv.z) SS1(a##i.w, bv.w)
        SSROW(0) SSROW(1) SSROW(2) SSROW(3) SSROW(4) SSROW(5) SSROW(6) SSROW(7)
    }

    // layer 3: single pass — h2 (16 pts x 512 = 32KB) in sbuf.
    // XOR swizzle: phys f4 (row, n4) = row*128 + ((n4 ^ row) & 127),
    // n4 = ch*64 + c. Store conflict-free; read 2-way = free.
    {
        const int n4 = ch * 64 + c;
#define L3ST(i) { const int rw = pg * 8 + (i); \
        *reinterpret_cast<float4*>(&sbuf[rw * 512 + ((n4 ^ rw) & 127) * 4]) = a##i; }
        L3ST(0) L3ST(1) L3ST(2) L3ST(3) L3ST(4) L3ST(5) L3ST(6) L3ST(7)
    }
    __syncthreads();

    {   // m = tid&15 (point), jg = tid>>4 (0..15) -> output cols jg*2, jg*2+1
        const int m  = tid & 15;
        const int jg = tid >> 4;
        const float* wr0 = np.w3 + (size_t)(jg * 2) * MID;
        const float* wr1 = wr0 + MID;
        float p0a = 0.f, p0b = 0.f, p1a = 0.f, p1b = 0.f;
        #pragma unroll 8
        for (int qq = 0; qq < 128; ++qq) {
            const float4 h  = *reinterpret_cast<const float4*>(
                &sbuf[m * 512 + ((qq ^ m) & 127) * 4]);
            const float4 w0 = *reinterpret_cast<const float4*>(wr0 + qq * 4);
            const float4 w1 = *reinterpret_cast<const float4*>(wr1 + qq * 4);
            p0a = fmaf(h.y, w0.y, fmaf(h.x, w0.x, p0a));
            p0b = fmaf(h.w, w0.w, fmaf(h.z, w0.z, p0b));
            p1a = fmaf(h.y, w1.y, fmaf(h.x, w1.x, p1a));
            p1b = fmaf(h.w, w1.w, fmaf(h.z, w1.z, p1b));
        }
        const float2 b3v = *reinterpret_cast<const float2*>(np.b3 + jg * 2);
        float2 r; r.x = p0a + p0b + b3v.x; r.y = p1a + p1b + b3v.y;
        *reinterpret_cast<float2*>(
            &P.table[((size_t)net * PTS + (m0 + m)) * 32 + jg * 2]) = r;
    }
}

// ---------------------------------------------------------------------------
// Kernel 2: Catmull-Rom interp + Tucker contraction — ROUND-6 VERSION VERBATIM
// (measured ~93us. R12 s_load variant ~145us; R7/R10 2-sample spilled.
// Do not touch.)
// ---------------------------------------------------------------------------
#define F4MA(acc, s, rp, k) { const float4 _v = (rp)[k]; \
    acc.x = fmaf((s), _v.x, acc.x); acc.y = fmaf((s), _v.y, acc.y); \
    acc.z = fmaf((s), _v.z, acc.z); acc.w = fmaf((s), _v.w, acc.w); }

#define GROW8(Pfx, w, rp, off) \
    F4MA(Pfx##0,(w),rp,(off)+0) F4MA(Pfx##1,(w),rp,(off)+1) \
    F4MA(Pfx##2,(w),rp,(off)+2) F4MA(Pfx##3,(w),rp,(off)+3) \
    F4MA(Pfx##4,(w),rp,(off)+4) F4MA(Pfx##5,(w),rp,(off)+5) \
    F4MA(Pfx##6,(w),rp,(off)+6) F4MA(Pfx##7,(w),rp,(off)+7)

// Catmull-Rom setup: x*G is EXACT in fp32 (power-of-two scale).
#define CRSETUP(x_, iv, c0, c1, c2, c3) \
    int iv; float c0, c1, c2, c3; { \
        float xx = (x_) * (float)G; \
        int i = (int)xx; i = i < 0 ? 0 : (i > G - 1 ? G - 1 : i); iv = i; \
        float t = xx - (float)i; \
        float t2 = t * t, t3 = t2 * t; \
        c0 = fmaf(-0.5f, t3, t2) - 0.5f * t; \
        c1 = fmaf(1.5f, t3, fmaf(-2.5f, t2, 1.f)); \
        c2 = fmaf(-1.5f, t3, fmaf(2.f, t2, 0.5f * t)); \
        c3 = 0.5f * (t3 - t2); }

__global__ __attribute__((amdgpu_waves_per_eu(2, 4))) __launch_bounds__(256)
void k_ic(const float* __restrict__ table, const float* __restrict__ core,
          const float* __restrict__ x, float* __restrict__ out)
{
    __shared__ float cs[8 * 1024];   // 32 KB: 8 r-rows of C per round
    __shared__ float red[256];

    const int tid = threadIdx.x;
    const int ls  = tid & 63;        // local sample
    const int rh  = tid >> 6;        // 0..3, wave-uniform; r = rb*8+rh*2+{0,1}
    const int g   = blockIdx.x * 64 + ls;

    const float xu = x[(size_t)g * 3 + 0];
    const float xv = x[(size_t)g * 3 + 1];
    const float xw = x[(size_t)g * 3 + 2];

#define DECLZ(Pn) float4 Pn = make_float4(0.f,0.f,0.f,0.f);
    DECLZ(W0) DECLZ(W1) DECLZ(W2) DECLZ(W3) DECLZ(W4) DECLZ(W5) DECLZ(W6) DECLZ(W7)
    DECLZ(V0) DECLZ(V1) DECLZ(V2) DECLZ(V3) DECLZ(V4) DECLZ(V5) DECLZ(V6) DECLZ(V7)
    float2 U0, U1, U2, U3;

    {   // W net (index 2)
        CRSETUP(xw, iw, c0, c1, c2, c3)
        const float4* rp = reinterpret_cast<const float4*>(
            table + ((size_t)2 * PTS + iw) * 32);
        GROW8(W, c0, rp, 0) GROW8(W, c1, rp, 8) GROW8(W, c2, rp, 16) GROW8(W, c3, rp, 24)
    }
    {   // V net (index 1)
        CRSETUP(xv, iv2, c0, c1, c2, c3)
        const float4* rp = reinterpret_cast<const float4*>(
            table + ((size_t)1 * PTS + iv2) * 32);
        GROW8(V, c0, rp, 0) GROW8(V, c1, rp, 8) GROW8(V, c2, rp, 16) GROW8(V, c3, rp, 24)
    }
    {   // U net (index 0): this thread's 8 r-cols = rb*8 + rh*2 + {0,1}
        CRSETUP(xu, iu, c0, c1, c2, c3)
        const float2* up = reinterpret_cast<const float2*>(table + (size_t)iu * 32);
#define UROW(rbv, dst) { \
        const float2 t0 = up[0 * 16 + (rbv) * 4 + rh]; \
        const float2 t1 = up[1 * 16 + (rbv) * 4 + rh]; \
        const float2 t2 = up[2 * 16 + (rbv) * 4 + rh]; \
        const float2 t3 = up[3 * 16 + (rbv) * 4 + rh]; \
        dst.x = fmaf(c0,t0.x,fmaf(c1,t1.x,fmaf(c2,t2.x,c3*t3.x))); \
        dst.y = fmaf(c0,t0.y,fmaf(c1,t1.y,fmaf(c2,t2.y,c3*t3.y))); }
        UROW(0, U0) UROW(1, U1) UROW(2, U2) UROW(3, U3)
    }

#define TQC(rl, s, tq, Wv) { \
    const float4 c4 = *reinterpret_cast<const float4*>( \
        &cs[(rh * 2 + (rl)) * 1024 + (s) * 32 + (tq) * 4]); \
    aa = fmaf(Wv.w, c4.w, fmaf(Wv.z, c4.z, fmaf(Wv.y, c4.y, fmaf(Wv.x, c4.x, aa)))); }

#define SONE(rl, s, vcomp) { float aa = 0.f; \
    TQC(rl, s, 0, W0) TQC(rl, s, 1, W1) TQC(rl, s, 2, W2) TQC(rl, s, 3, W3) \
    TQC(rl, s, 4, W4) TQC(rl, s, 5, W5) TQC(rl, s, 6, W6) TQC(rl, s, 7, W7) \
    tracc = fmaf(vcomp, aa, tracc); }

#define SG(rl, sb, Vv) \
    SONE(rl, 4*(sb)+0, Vv.x) SONE(rl, 4*(sb)+1, Vv.y) \
    SONE(rl, 4*(sb)+2, Vv.z) SONE(rl, 4*(sb)+3, Vv.w)

#define RL1(rl, ucomp) { float tracc = 0.f; \
    SG(rl, 0, V0) SG(rl, 1, V1) SG(rl, 2, V2) SG(rl, 3, V3) \
    SG(rl, 4, V4) SG(rl, 5, V5) SG(rl, 6, V6) SG(rl, 7, V7) \
    o = fmaf(ucomp, tracc, o); }

#define RBLOCK(rb) { \
    __syncthreads(); \
    _Pragma("unroll") \
    for (int cc = 0; cc < 8; ++cc) \
        *reinterpret_cast<float4*>(&cs[cc * 1024 + tid * 4]) = \
            *reinterpret_cast<const float4*>(core + (size_t)((rb) * 8 + cc) * 1024 + tid * 4); \
    __syncthreads(); \
    RL1(0, U##rb.x) RL1(1, U##rb.y) }

    float o = 0.f;
    RBLOCK(0) RBLOCK(1) RBLOCK(2) RBLOCK(3)

    red[tid] = o;
    __syncthreads();
    if (tid < 64)
        out[blockIdx.x * 64 + tid] =
            red[tid] + red[tid + 64] + red[tid + 128] + red[tid + 192];
}

// ---------------------------------------------------------------------------
extern "C" void kernel_launch(void* const* d_in, const int* in_sizes, int n_in,
                              void* d_out, int out_size, void* d_ws, size_t ws_size,
                              hipStream_t stream)
{
    AllP P;
    for (int net = 0; net < 3; ++net) {
        const int b = 1 + net * 6;
        P.n[net].w1 = (const float*)d_in[b + 0];
        P.n[net].b1 = (const float*)d_in[b + 1];
        P.n[net].w2 = (const float*)d_in[b + 2];
        P.n[net].b2 = (const float*)d_in[b + 3];
        P.n[net].w3 = (const float*)d_in[b + 4];
        P.n[net].b3 = (const float*)d_in[b + 5];
    }
    const float* xin  = (const float*)d_in[0];
    const float* core = (const float*)d_in[19];
    float* wsf   = (float*)d_ws;
    float* table = wsf;                            // 3*4128*32 = 1.58 MB
    float* w2t   = wsf + (size_t)3 * PTS * 32;     // 3*512*512 = 3.00 MB
    P.table = table;

    k_prep <<<dim3(16, 16, 3), 256, 0, stream>>>(P, w2t);
    k_siren<<<dim3(NBLK, 3), 256, 0, stream>>>(P, w2t);
    k_ic   <<<NB / 64, 256, 0, stream>>>(table, core, xin, (float*)d_out);
}